// Round 3
// baseline (345.751 us; speedup 1.0000x reference)
//
#include <hip/hip_runtime.h>
#include <hip/hip_bf16.h>

#define N_PATHS   10000000
#define MAX_LEN   3
#define HIDDEN    128
#define PPT       8   // paths per thread

typedef int   v4i __attribute__((ext_vector_type(4)));
typedef float v4f __attribute__((ext_vector_type(4)));

// Kernel 1: proj[l * n_nodes + node] = dot(node_feature[node, :], W[l, 0, :])
// One wave (64 lanes) per node; lane i holds float2 = elements {2i, 2i+1}.
__global__ __launch_bounds__(256) void proj_kernel(
    const float* __restrict__ feat,   // (n_nodes, 128)
    const float* __restrict__ W,      // (3, 1, 128)
    float* __restrict__ proj,         // (3, n_nodes)
    int n_nodes)
{
    int gtid = blockIdx.x * blockDim.x + threadIdx.x;
    int node = gtid >> 6;
    int lane = threadIdx.x & 63;
    if (node >= n_nodes) return;

    const float2* f2 = (const float2*)(feat + (size_t)node * HIDDEN);
    const float2* w2 = (const float2*)W;

    float2 f   = f2[lane];
    float2 w0  = w2[lane];           // W[0]
    float2 w1  = w2[64 + lane];      // W[1]
    float2 w2v = w2[128 + lane];     // W[2]

    float s0 = f.x * w0.x  + f.y * w0.y;
    float s1 = f.x * w1.x  + f.y * w1.y;
    float s2 = f.x * w2v.x + f.y * w2v.y;

    #pragma unroll
    for (int off = 32; off > 0; off >>= 1) {
        s0 += __shfl_xor(s0, off, 64);
        s1 += __shfl_xor(s1, off, 64);
        s2 += __shfl_xor(s2, off, 64);
    }

    if (lane == 0) {
        proj[0 * n_nodes + node] = s0;
        proj[1 * n_nodes + node] = s1;
        proj[2 * n_nodes + node] = s2;
    }
}

// Kernel 2: 8 paths per thread. 6 aligned int4 path loads + 24 gathers all
// in flight before any consumption -> ~30 outstanding VMEM ops/thread.
// Little's law: 24 waves/CU * 24 gathers = ~576 in-flight requests/CU,
// ~2x round 2. Streaming accesses stay non-temporal to keep the 1.2 MB
// proj table L2-resident.
__global__ __launch_bounds__(256, 8) void score_kernel(
    const int* __restrict__ paths,    // (n_paths, 3) int32
    const float* __restrict__ proj,   // (3, n_nodes)
    float* __restrict__ out,          // (n_paths,)
    int n_nodes, int n_threads)
{
    int t = blockIdx.x * blockDim.x + threadIdx.x;
    if (t >= n_threads) return;

    // 8 paths = 24 ints = 6 int4 loads
    const v4i* p4 = (const v4i*)paths;
    v4i pv[6];
    #pragma unroll
    for (int i = 0; i < 6; ++i)
        pv[i] = __builtin_nontemporal_load(p4 + 6 * t + i);

    int ids[24];
    #pragma unroll
    for (int i = 0; i < 6; ++i) {
        ids[4 * i + 0] = pv[i].x;
        ids[4 * i + 1] = pv[i].y;
        ids[4 * i + 2] = pv[i].z;
        ids[4 * i + 3] = pv[i].w;
    }

    // Issue all 24 gathers before any use (max MLP). Unsigned compare
    // folds the id<0 and id>=n_nodes checks into one.
    float g[24];
    #pragma unroll
    for (int k = 0; k < 24; ++k) {
        int id = ids[k];
        bool valid = (unsigned)id < (unsigned)n_nodes;
        int safe = valid ? id : 0;
        g[k] = proj[(k % 3) * n_nodes + safe];
    }

    v4f o0, o1;
    #pragma unroll
    for (int j = 0; j < 8; ++j) {
        bool v0 = (unsigned)ids[j * 3 + 0] < (unsigned)n_nodes;
        bool v1 = (unsigned)ids[j * 3 + 1] < (unsigned)n_nodes;
        bool v2 = (unsigned)ids[j * 3 + 2] < (unsigned)n_nodes;
        float s = (v0 ? g[j * 3 + 0] : 0.0f)
                + (v1 ? g[j * 3 + 1] : 0.0f)
                + (v2 ? g[j * 3 + 2] : 0.0f);
        int cnt = (int)v0 + (int)v1 + (int)v2;
        float inv = (cnt == 3) ? (1.0f / 3.0f) : ((cnt == 2) ? 0.5f : 1.0f);
        float r = s * inv;
        if (j < 4) o0[j] = r; else o1[j - 4] = r;
    }
    __builtin_nontemporal_store(o0, ((v4f*)out) + 2 * t + 0);
    __builtin_nontemporal_store(o1, ((v4f*)out) + 2 * t + 1);
}

extern "C" void kernel_launch(void* const* d_in, const int* in_sizes, int n_in,
                              void* d_out, int out_size, void* d_ws, size_t ws_size,
                              hipStream_t stream) {
    const int*   paths = (const int*)d_in[0];     // (N_PATHS, 3) int32
    const float* feat  = (const float*)d_in[1];   // (N_NODES, 128) f32
    const float* W     = (const float*)d_in[2];   // (3, 1, 128) f32
    float*       out   = (float*)d_out;           // (N_PATHS,) f32

    const int n_nodes = in_sizes[1] / HIDDEN;     // 100000
    float* proj = (float*)d_ws;                   // 3 * n_nodes floats = 1.2 MB

    // Kernel 1: 1 wave per node, 4 waves per 256-thread block.
    {
        int blocks = (n_nodes + 3) / 4;
        proj_kernel<<<blocks, 256, 0, stream>>>(feat, W, proj, n_nodes);
    }

    // Kernel 2: 8 paths per thread.
    {
        int n_threads = N_PATHS / PPT;            // 1,250,000
        int blocks = (n_threads + 255) / 256;
        score_kernel<<<blocks, 256, 0, stream>>>(paths, proj, out, n_nodes, n_threads);
    }
}

// Round 4
// 328.183 us; speedup vs baseline: 1.0535x; 1.0535x over previous
//
#include <hip/hip_runtime.h>
#include <hip/hip_bf16.h>

#define N_PATHS   10000000
#define MAX_LEN   3
#define HIDDEN    128

typedef int   v4i __attribute__((ext_vector_type(4)));
typedef float v4f __attribute__((ext_vector_type(4)));

// Raw buffer load with cache-policy aux bits. On gfx950, aux bit0 (glc)
// assembles as sc0 => bypass/no-allocate vector L1, normal L2 caching.
__device__ float llvm_amdgcn_raw_buffer_load_fp32(v4i srsrc, int voffset,
                                                  int soffset, int aux)
    __asm("llvm.amdgcn.raw.buffer.load.f32");

__device__ inline v4i make_srd(const void* p, unsigned bytes) {
    union {
        v4i v;
        struct { const void* base; unsigned num; unsigned cfg; } s;
    } u;
    u.s.base = p;
    u.s.num  = bytes;          // num_records in bytes (stride==0)
    u.s.cfg  = 0x00020000;     // raw dword access
    return u.v;
}

// proj layout: 3 planes of stride (n_nodes+1); slot 0 of each plane is a
// zero pad so id == -1 gathers 0.0 with no clamp/select.
// Kernel 1: proj[l*(n_nodes+1) + 1 + node] = dot(feat[node,:], W[l,0,:]).
// One wave per node; lane i holds float2 = elements {2i, 2i+1}.
__global__ __launch_bounds__(256) void proj_kernel(
    const float* __restrict__ feat,   // (n_nodes, 128)
    const float* __restrict__ W,      // (3, 1, 128)
    float* __restrict__ proj,         // (3, n_nodes+1)
    int n_nodes)
{
    // zero the three pad slots (d_ws is poisoned before every launch)
    if (blockIdx.x == 0 && threadIdx.x < 3)
        proj[(size_t)threadIdx.x * (n_nodes + 1)] = 0.0f;

    int gtid = blockIdx.x * blockDim.x + threadIdx.x;
    int node = gtid >> 6;
    int lane = threadIdx.x & 63;
    if (node >= n_nodes) return;

    const float2* f2 = (const float2*)(feat + (size_t)node * HIDDEN);
    const float2* w2 = (const float2*)W;

    float2 f   = f2[lane];
    float2 w0  = w2[lane];           // W[0]
    float2 w1  = w2[64 + lane];      // W[1]
    float2 w2v = w2[128 + lane];     // W[2]

    float s0 = f.x * w0.x  + f.y * w0.y;
    float s1 = f.x * w1.x  + f.y * w1.y;
    float s2 = f.x * w2v.x + f.y * w2v.y;

    #pragma unroll
    for (int off = 32; off > 0; off >>= 1) {
        s0 += __shfl_xor(s0, off, 64);
        s1 += __shfl_xor(s1, off, 64);
        s2 += __shfl_xor(s2, off, 64);
    }

    if (lane == 0) {
        int stride = n_nodes + 1;
        proj[0 * stride + 1 + node] = s0;
        proj[1 * stride + 1 + node] = s1;
        proj[2 * stride + 1 + node] = s2;
    }
}

// Kernel 2: 4 paths/thread. Gathers use sc0 (L1-bypass) buffer loads to
// skip the L1 miss-fill-replay serialization; paths/out stay non-temporal
// so L2 holds only the 1.2 MB proj table.
__global__ __launch_bounds__(256) void score_kernel(
    const int* __restrict__ paths,    // (n_paths, 3) int32
    const float* __restrict__ proj,   // (3, n_nodes+1)
    float* __restrict__ out,          // (n_paths,)
    int n_nodes, int n_quads)
{
    int t = blockIdx.x * blockDim.x + threadIdx.x;
    if (t >= n_quads) return;

    int stride = n_nodes + 1;
    v4i srd = make_srd(proj, (unsigned)(3 * stride) * 4u);

    const v4i* p4 = (const v4i*)paths;
    v4i a = __builtin_nontemporal_load(p4 + 3 * t + 0);
    v4i b = __builtin_nontemporal_load(p4 + 3 * t + 1);
    v4i c = __builtin_nontemporal_load(p4 + 3 * t + 2);

    int ids[12] = { a.x, a.y, a.z, a.w,
                    b.x, b.y, b.z, b.w,
                    c.x, c.y, c.z, c.w };

    // Issue all 12 gathers (sc0) before any use. id == -1 hits the zero
    // pad slot of its plane; valid ids land at +1.
    float g[12];
    #pragma unroll
    for (int k = 0; k < 12; ++k) {
        int voff = ((k % 3) * stride + 1 + ids[k]) * 4;
        g[k] = llvm_amdgcn_raw_buffer_load_fp32(srd, voff, 0, 1 /*sc0*/);
    }

    v4f o;
    #pragma unroll
    for (int j = 0; j < 4; ++j) {
        float s = g[j * 3 + 0] + g[j * 3 + 1] + g[j * 3 + 2];
        int cnt = (int)(ids[j * 3 + 0] >= 0)
                + (int)(ids[j * 3 + 1] >= 0)
                + (int)(ids[j * 3 + 2] >= 0);
        float inv = (cnt == 3) ? (1.0f / 3.0f) : ((cnt == 2) ? 0.5f : 1.0f);
        o[j] = s * inv;
    }
    __builtin_nontemporal_store(o, ((v4f*)out) + t);
}

extern "C" void kernel_launch(void* const* d_in, const int* in_sizes, int n_in,
                              void* d_out, int out_size, void* d_ws, size_t ws_size,
                              hipStream_t stream) {
    const int*   paths = (const int*)d_in[0];     // (N_PATHS, 3) int32
    const float* feat  = (const float*)d_in[1];   // (N_NODES, 128) f32
    const float* W     = (const float*)d_in[2];   // (3, 1, 128) f32
    float*       out   = (float*)d_out;           // (N_PATHS,) f32

    const int n_nodes = in_sizes[1] / HIDDEN;     // 100000
    float* proj = (float*)d_ws;                   // 3*(n_nodes+1) floats

    // Kernel 1: 1 wave per node, 4 waves per 256-thread block.
    {
        int blocks = (n_nodes + 3) / 4;
        proj_kernel<<<blocks, 256, 0, stream>>>(feat, W, proj, n_nodes);
    }

    // Kernel 2: 4 paths per thread.
    {
        int n_quads = N_PATHS / 4;                // 2,500,000
        int blocks = (n_quads + 255) / 256;
        score_kernel<<<blocks, 256, 0, stream>>>(paths, proj, out, n_nodes, n_quads);
    }
}